// Round 1
// baseline (29863.409 us; speedup 1.0000x reference)
//
#include <hip/hip_runtime.h>
#include <stdint.h>
#include <math.h>

// Seq2seq LSTM: persistent-grid recurrence (enc 2048 + dec 512 steps) with
// bf16 weight slices in LDS + 2-level spin barrier; then one bf16-MFMA GEMM
// (512 x 50257 x 1024) for the output head; then row softmax in-place.
//
// ws layout: [0]      root counter + group counters (u32, 128B-spaced)
//            [4096]   h double buffer: 2 x 1024 f32
//            [16384]  Adec: decoder hidden states, T x 1024 bf16 (1 MB)

typedef __attribute__((ext_vector_type(8))) short short8;
typedef __attribute__((ext_vector_type(4))) float f32x4;

#define HD 1024
#define ED 512
#define LEN 1536
#define TPB 256
#define NWG 256

__device__ __forceinline__ unsigned short f2bf(float f) {
  union { float f; unsigned u; } x; x.f = f;
  unsigned u = x.u;
  u += 0x7fffu + ((u >> 16) & 1u);        // RNE
  return (unsigned short)(u >> 16);
}
__device__ __forceinline__ float bflo(unsigned u) {
  union { unsigned u; float f; } x; x.u = u << 16; return x.f;
}
__device__ __forceinline__ float bfhi(unsigned u) {
  union { unsigned u; float f; } x; x.u = u & 0xffff0000u; return x.f;
}
__device__ __forceinline__ float sigmf(float x) { return 1.0f / (1.0f + expf(-x)); }

// Load this WG's 16 gate rows ([Whh | Wih] concat, bf16) + bias into LDS.
// LDS row r = u*4 + gt  <->  global gate row gt*H + hu0 + u   (gt: 0=i,1=f,2=g,3=o)
__device__ __forceinline__ void load_wgt(unsigned short (*wgt)[LEN], float* bias, int hu0,
                                         const float* __restrict__ Whh,
                                         const float* __restrict__ Wih,
                                         const float* __restrict__ b1,
                                         const float* __restrict__ b2) {
  const int tid = threadIdx.x;
  for (int idx = tid; idx < 16 * LEN; idx += TPB) {
    int r = idx / LEN, ccol = idx - r * LEN;
    int gt = r & 3, u = r >> 2;
    int grow = gt * HD + hu0 + u;
    float w;
    if (ccol < HD)      w = Whh[grow * HD + ccol];
    else if (Wih)       w = Wih[grow * ED + (ccol - HD)];
    else                w = 0.0f;
    wgt[r][ccol] = f2bf(w);
  }
  if (tid < 16) {
    int gt = tid & 3, u = tid >> 2;
    int grow = gt * HD + hu0 + u;
    bias[tid] = b1[grow] + b2[grow];
  }
}

__global__ __launch_bounds__(TPB)
void rnn_kernel(const int* __restrict__ state,
                const float* __restrict__ emb,
                const float* __restrict__ encWih,
                const float* __restrict__ encWhh,
                const float* __restrict__ encbih,
                const float* __restrict__ encbhh,
                const float* __restrict__ decWhh,
                const float* __restrict__ decbih,
                const float* __restrict__ decbhh,
                unsigned* __restrict__ ctr,
                float* __restrict__ hb,            // [2][1024] f32
                unsigned short* __restrict__ Adec, // [T][1024] bf16
                int S, int T) {
  __shared__ __align__(16) unsigned short wgt[16][LEN]; // 48 KB
  __shared__ __align__(16) float vec[LEN];              // [h | x] staging
  __shared__ float bias[16];
  __shared__ float gsh[16];

  const int tid = threadIdx.x;
  const int wg  = blockIdx.x;
  const int hu0 = wg << 2;       // 4 hidden units per WG
  const int row = tid >> 4;      // 16 threads per gate row
  const int c   = tid & 15;

  float ccell = 0.0f;            // cell state (threads 0..3 only)
  unsigned bid = 0;

  load_wgt(wgt, bias, hu0, encWhh, encWih, encbih, encbhh);
  __syncthreads();

  for (int t = 0; t < S + T; ++t) {
    const bool dec = (t >= S);
    if (t == S) {
      // switch to decoder weights; x-part of vec stays zero from here on
      load_wgt(wgt, bias, hu0, decWhh, nullptr, decbih, decbhh);
      if (tid < 128) ((float4*)(vec + HD))[tid] = make_float4(0.f, 0.f, 0.f, 0.f);
      __syncthreads();
    }
    // ---- stage h (and x for encoder) into LDS ----
    {
      const float4* hp = (const float4*)(hb + (t & 1) * HD);
      ((float4*)vec)[tid] = hp[tid];
      if (!dec && tid < 128) {
        int tok = state[t];
        ((float4*)(vec + HD))[tid] = ((const float4*)(emb + (size_t)tok * ED))[tid];
      }
    }
    __syncthreads();
    // ---- dot: each thread covers 12 interleaved 8-col chunks of its row ----
    float acc = (c == 0) ? bias[row] : 0.0f;
#pragma unroll
    for (int j = 0; j < 12; ++j) {
      const int cb = (c + (j << 4)) << 3;   // (c + 16j)*8
      uint4 w = *(const uint4*)&wgt[row][cb];
      const float4* vp = (const float4*)&vec[cb];
      float4 va = vp[0];
      float4 vb = vp[1];
      acc = fmaf(bflo(w.x), va.x, acc);
      acc = fmaf(bfhi(w.x), va.y, acc);
      acc = fmaf(bflo(w.y), va.z, acc);
      acc = fmaf(bfhi(w.y), va.w, acc);
      acc = fmaf(bflo(w.z), vb.x, acc);
      acc = fmaf(bfhi(w.z), vb.y, acc);
      acc = fmaf(bflo(w.w), vb.z, acc);
      acc = fmaf(bfhi(w.w), vb.w, acc);
    }
    // reduce 16 threads per row (xor masks stay inside 16-lane groups)
    acc += __shfl_xor(acc, 1);
    acc += __shfl_xor(acc, 2);
    acc += __shfl_xor(acc, 4);
    acc += __shfl_xor(acc, 8);
    if (c == 0) gsh[row] = acc;
    __syncthreads();
    // ---- LSTM cell on 4 threads, write h slice ----
    if (tid < 4) {
      float gi = gsh[(tid << 2) + 0];
      float gf = gsh[(tid << 2) + 1];
      float gg = gsh[(tid << 2) + 2];
      float go = gsh[(tid << 2) + 3];
      float iv = sigmf(gi), fv = sigmf(gf), gv = tanhf(gg), ov = sigmf(go);
      ccell = fv * ccell + iv * gv;
      float hv = ov * tanhf(ccell);
      hb[((t + 1) & 1) * HD + hu0 + tid] = hv;
      if (dec) Adec[(size_t)(t - S) * HD + hu0 + tid] = f2bf(hv);
    }
    // ---- 2-level grid barrier (16 groups x 16 WGs -> root) ----
    ++bid;
    __syncthreads();                       // h stores drained to L2 before fence
    if (tid == 0) {
      __threadfence();                     // release: flush to device scope
      unsigned old = atomicAdd(&ctr[32 + ((wg >> 4) << 5)], 1u);
      if (old + 1u == bid * 16u) atomicAdd(&ctr[0], 1u); // last of group arrives at root
      const unsigned tgt = bid * 16u;      // root += 16 per step
      while (__hip_atomic_load(&ctr[0], __ATOMIC_RELAXED, __HIP_MEMORY_SCOPE_AGENT) < tgt) {}
      __threadfence();                     // acquire: invalidate stale cache lines
    }
    __syncthreads();
  }
}

// ---- output head GEMM: out[t][v] = Adec[t] . Wout[v] + bout[v] ----
// WG tile: 512 t x 64 v. Wave w: t in [w*128, w*128+128), v in [v0, v0+64).
// Per k-step (K=32): stage A-slice (512x32 bf16, padded stride) in LDS,
// 8 a-frags + 4 b-frags -> 32 MFMA per wave. Wout (206 MB) read exactly once.
#define AST 56   // Alds row stride in ushorts (112B = 7*16B, conflict-free-ish)

__global__ __launch_bounds__(TPB)
void out_gemm(const unsigned short* __restrict__ Adec,
              const float* __restrict__ Wout,
              const float* __restrict__ bout,
              float* __restrict__ out,
              int V) {
  __shared__ __align__(16) unsigned short Alds[512 * AST]; // 56 KB
  const int tid  = threadIdx.x;
  const int wv   = tid >> 6;
  const int lane = tid & 63;
  const int col  = lane & 15;
  const int quad = lane >> 4;
  const int v0   = blockIdx.x * 64;

  f32x4 acc[4][8];
#pragma unroll
  for (int bt = 0; bt < 4; ++bt)
#pragma unroll
    for (int tt = 0; tt < 8; ++tt)
      acc[bt][tt] = (f32x4){0.f, 0.f, 0.f, 0.f};

  for (int k0 = 0; k0 < HD; k0 += 32) {
    __syncthreads();
    // stage A k-slice: 512 rows x 32 bf16 (4 x uint4 chunks per row)
#pragma unroll
    for (int i = 0; i < 8; ++i) {
      int id = tid + (i << 8);             // 0..2047
      int rt = id >> 2, c4 = id & 3;
      uint4 d = *(const uint4*)(Adec + rt * HD + k0 + (c4 << 3));
      *(uint4*)&Alds[rt * AST + (c4 << 3)] = d;
    }
    __syncthreads();
    // B fragments from global (fp32 -> bf16): lane l covers Wout[v0+bt*16+col][k0+quad*8 ..+7]
    short8 bf[4];
#pragma unroll
    for (int bt = 0; bt < 4; ++bt) {
      int v = v0 + (bt << 4) + col;
      if (v >= V) v = V - 1;
      const float4* wp = (const float4*)(Wout + (size_t)v * HD + k0 + (quad << 3));
      float4 w0 = wp[0], w1 = wp[1];
      short8 b;
      b[0] = (short)f2bf(w0.x); b[1] = (short)f2bf(w0.y);
      b[2] = (short)f2bf(w0.z); b[3] = (short)f2bf(w0.w);
      b[4] = (short)f2bf(w1.x); b[5] = (short)f2bf(w1.y);
      b[6] = (short)f2bf(w1.z); b[7] = (short)f2bf(w1.w);
      bf[bt] = b;
    }
#pragma unroll
    for (int tt = 0; tt < 8; ++tt) {
      int trow = (wv << 7) + (tt << 4) + col;
      short8 af = *(const short8*)&Alds[trow * AST + (quad << 3)];
#pragma unroll
      for (int bt = 0; bt < 4; ++bt)
        acc[bt][tt] = __builtin_amdgcn_mfma_f32_16x16x32_bf16(af, bf[bt], acc[bt][tt], 0, 0, 0);
    }
  }
  // epilogue: C/D layout col = lane&15 (v), row = quad*4 + reg (t)
#pragma unroll
  for (int bt = 0; bt < 4; ++bt) {
    int v = v0 + (bt << 4) + col;
    if (v < V) {
      float bb = bout[v];
#pragma unroll
      for (int tt = 0; tt < 8; ++tt) {
        int tb = (wv << 7) + (tt << 4) + (quad << 2);
        f32x4 a = acc[bt][tt];
        out[(size_t)(tb + 0) * V + v] = a[0] + bb;
        out[(size_t)(tb + 1) * V + v] = a[1] + bb;
        out[(size_t)(tb + 2) * V + v] = a[2] + bb;
        out[(size_t)(tb + 3) * V + v] = a[3] + bb;
      }
    }
  }
}

// ---- row softmax in place over d_out: one WG per t ----
__global__ __launch_bounds__(TPB)
void softmax_rows(float* __restrict__ out, int V) {
  float* rowp = out + (size_t)blockIdx.x * V;
  __shared__ float red[8];
  const int tid = threadIdx.x;

  float m = -1e30f;
  for (int v = tid; v < V; v += TPB) m = fmaxf(m, rowp[v]);
#pragma unroll
  for (int off = 32; off >= 1; off >>= 1) m = fmaxf(m, __shfl_xor(m, off));
  if ((tid & 63) == 0) red[tid >> 6] = m;
  __syncthreads();
  if (tid == 0) red[4] = fmaxf(fmaxf(red[0], red[1]), fmaxf(red[2], red[3]));
  __syncthreads();
  m = red[4];

  float s = 0.0f;
  for (int v = tid; v < V; v += TPB) {
    float e = expf(rowp[v] - m);
    rowp[v] = e;
    s += e;
  }
#pragma unroll
  for (int off = 32; off >= 1; off >>= 1) s += __shfl_xor(s, off);
  if ((tid & 63) == 0) red[tid >> 6] = s;
  __syncthreads();
  if (tid == 0) red[5] = red[0] + red[1] + red[2] + red[3];
  __syncthreads();
  float inv = 1.0f / red[5];
  for (int v = tid; v < V; v += TPB) rowp[v] *= inv;
}

extern "C" void kernel_launch(void* const* d_in, const int* in_sizes, int n_in,
                              void* d_out, int out_size, void* d_ws, size_t ws_size,
                              hipStream_t stream) {
  const int*   state  = (const int*)d_in[0];
  // d_in[1] = max_len scalar (T derived from out_size instead)
  const float* emb    = (const float*)d_in[2];
  const float* encWih = (const float*)d_in[3];
  const float* encWhh = (const float*)d_in[4];
  const float* encbih = (const float*)d_in[5];
  const float* encbhh = (const float*)d_in[6];
  // d_in[7] = dec_Wih (multiplied by zero input in reference -> unused)
  const float* decWhh = (const float*)d_in[8];
  const float* decbih = (const float*)d_in[9];
  const float* decbhh = (const float*)d_in[10];
  const float* Wout   = (const float*)d_in[11];
  const float* bout   = (const float*)d_in[12];
  float*       out    = (float*)d_out;

  const int S = in_sizes[0];          // 2048
  const int V = in_sizes[12];         // 50257
  const int T = out_size / V;         // 512

  // zero counters + h double-buffer (ws is poisoned before every call)
  hipMemsetAsync(d_ws, 0, 16384, stream);
  unsigned*       ctr  = (unsigned*)d_ws;
  float*          hb   = (float*)((char*)d_ws + 4096);
  unsigned short* Adec = (unsigned short*)((char*)d_ws + 16384);

  rnn_kernel<<<NWG, TPB, 0, stream>>>(state, emb, encWih, encWhh, encbih, encbhh,
                                      decWhh, decbih, decbhh, ctr, hb, Adec, S, T);
  int nvb = (V + 63) / 64;
  out_gemm<<<nvb, TPB, 0, stream>>>(Adec, Wout, bout, out, V);
  softmax_rows<<<T, TPB, 0, stream>>>(out, V);
}

// Round 2
// 9364.255 us; speedup vs baseline: 3.1891x; 3.1891x over previous
//
#include <hip/hip_runtime.h>
#include <stdint.h>
#include <math.h>

// Seq2seq LSTM: persistent-grid recurrence (enc 2048 + dec 512 steps) with
// bf16 weight slices in LDS + contention-free sc1 flag barrier; then one
// bf16-MFMA GEMM (512 x 50257 x 1024) for the output head; then row softmax.
//
// Barrier design (round 2): every cross-WG datum lives on its own 64B line
// and is accessed ONLY via agent-scope relaxed atomics (sc1 -> LLC coherent).
//   arrived[wg]  (d_ws + 0      + wg*64): producer writes step id (no RMW)
//   flag[wg]     (d_ws + 16384  + wg*64): root WG0 writes release step id
//   hb           (d_ws + 32768): 2 x 1024 f32 double-buffered hidden state
//   Adec         (d_ws + 49152): T x 1024 bf16 decoder hidden states
// No threadfence / buffer_wbl2 / buffer_inv anywhere: ordering is
// s_waitcnt vmcnt(0) (per-wave store drain) before the arrived store.

typedef __attribute__((ext_vector_type(8))) short short8;
typedef __attribute__((ext_vector_type(4))) float f32x4;

#define HD 1024
#define ED 512
#define LEN 1536
#define PLEN 1552   // padded wgt row stride: 3104 B = 32 mod 128 -> rows hit disjoint bank quarters
#define TPB 256
#define NWG 256
#define FS 16       // flag stride in u32 (64 B)

#define AGT __HIP_MEMORY_SCOPE_AGENT
#define RLX __ATOMIC_RELAXED

__device__ __forceinline__ unsigned short f2bf(float f) {
  union { float f; unsigned u; } x; x.f = f;
  unsigned u = x.u;
  u += 0x7fffu + ((u >> 16) & 1u);        // RNE
  return (unsigned short)(u >> 16);
}
__device__ __forceinline__ float bflo(unsigned u) {
  union { unsigned u; float f; } x; x.u = u << 16; return x.f;
}
__device__ __forceinline__ float bfhi(unsigned u) {
  union { unsigned u; float f; } x; x.u = u & 0xffff0000u; return x.f;
}
__device__ __forceinline__ float sigmf(float x) { return 1.0f / (1.0f + expf(-x)); }

// Load this WG's 16 gate rows ([Whh | Wih] concat, bf16) + bias into LDS.
// LDS row r = u*4 + gt  <->  global gate row gt*H + hu0 + u   (gt: 0=i,1=f,2=g,3=o)
__device__ __forceinline__ void load_wgt(unsigned short (*wgt)[PLEN], float* bias, int hu0,
                                         const float* __restrict__ Whh,
                                         const float* __restrict__ Wih,
                                         const float* __restrict__ b1,
                                         const float* __restrict__ b2) {
  const int tid = threadIdx.x;
  for (int idx = tid; idx < 16 * LEN; idx += TPB) {
    int r = idx / LEN, ccol = idx - r * LEN;
    int gt = r & 3, u = r >> 2;
    int grow = gt * HD + hu0 + u;
    float w;
    if (ccol < HD)      w = Whh[grow * HD + ccol];
    else if (Wih)       w = Wih[grow * ED + (ccol - HD)];
    else                w = 0.0f;
    wgt[r][ccol] = f2bf(w);
  }
  if (tid < 16) {
    int gt = tid & 3, u = tid >> 2;
    int grow = gt * HD + hu0 + u;
    bias[tid] = b1[grow] + b2[grow];
  }
}

__global__ __launch_bounds__(TPB)
void rnn_kernel(const int* __restrict__ state,
                const float* __restrict__ emb,
                const float* __restrict__ encWih,
                const float* __restrict__ encWhh,
                const float* __restrict__ encbih,
                const float* __restrict__ encbhh,
                const float* __restrict__ decWhh,
                const float* __restrict__ decbih,
                const float* __restrict__ decbhh,
                unsigned* __restrict__ arrived,    // [NWG] at 64B stride
                unsigned* __restrict__ flag,       // [NWG] at 64B stride
                float* __restrict__ hb,            // [2][1024] f32
                unsigned short* __restrict__ Adec, // [T][1024] bf16
                int S, int T) {
  __shared__ __align__(16) unsigned short wgt[16][PLEN]; // ~48.5 KB
  __shared__ __align__(16) float vec[LEN];               // [h | x] staging
  __shared__ float bias[16];
  __shared__ float gsh[16];

  const int tid = threadIdx.x;
  const int wg  = blockIdx.x;
  const int hu0 = wg << 2;       // 4 hidden units per WG
  const int row = tid >> 4;      // 16 threads per gate row
  const int c   = tid & 15;

  float ccell = 0.0f;            // cell state (threads 0..3 only)

  load_wgt(wgt, bias, hu0, encWhh, encWih, encbih, encbhh);
  // stage x_0
  if (tid < 128) {
    int tok = state[0];
    ((float4*)(vec + HD))[tid] = ((const float4*)(emb + (size_t)tok * ED))[tid];
  }
  __syncthreads();

  for (int t = 0; t < S + T; ++t) {
    const bool dec = (t >= S);
    // ---- wait for previous step's release (private flag line) ----
    if (t > 0) {
      if (tid == 0) {
        while (__hip_atomic_load(&flag[wg * FS], RLX, AGT) < (unsigned)t) {}
      }
      __syncthreads();
    }
    // ---- decoder switch: new weights, x stays zero from here on ----
    if (t == S) {
      load_wgt(wgt, bias, hu0, decWhh, nullptr, decbih, decbhh);
      if (tid < 128) ((float4*)(vec + HD))[tid] = make_float4(0.f, 0.f, 0.f, 0.f);
    }
    // ---- consumer: hb[t&1] -> vec[0..HD) via sc1 loads (LLC-coherent) ----
    {
      unsigned long long* hsrc = (unsigned long long*)(hb + (t & 1) * HD);
      unsigned long long d0 = __hip_atomic_load(&hsrc[tid * 2 + 0], RLX, AGT);
      unsigned long long d1 = __hip_atomic_load(&hsrc[tid * 2 + 1], RLX, AGT);
      union { unsigned long long u; float2 f; } a, b;
      a.u = d0; b.u = d1;
      *(float2*)&vec[tid * 4 + 0] = a.f;
      *(float2*)&vec[tid * 4 + 2] = b.f;
    }
    __syncthreads();
    // ---- dot: each thread covers 12 interleaved 8-col chunks of its row ----
    float acc = (c == 0) ? bias[row] : 0.0f;
#pragma unroll
    for (int j = 0; j < 12; ++j) {
      const int cb = (c + (j << 4)) << 3;   // (c + 16j)*8
      uint4 w = *(const uint4*)&wgt[row][cb];
      const float4* vp = (const float4*)&vec[cb];
      float4 va = vp[0];
      float4 vb = vp[1];
      acc = fmaf(bflo(w.x), va.x, acc);
      acc = fmaf(bfhi(w.x), va.y, acc);
      acc = fmaf(bflo(w.y), va.z, acc);
      acc = fmaf(bfhi(w.y), va.w, acc);
      acc = fmaf(bflo(w.z), vb.x, acc);
      acc = fmaf(bfhi(w.z), vb.y, acc);
      acc = fmaf(bflo(w.w), vb.z, acc);
      acc = fmaf(bfhi(w.w), vb.w, acc);
    }
    // reduce 16 threads per row (xor masks stay inside 16-lane groups)
    acc += __shfl_xor(acc, 1);
    acc += __shfl_xor(acc, 2);
    acc += __shfl_xor(acc, 4);
    acc += __shfl_xor(acc, 8);
    if (c == 0) gsh[row] = acc;
    __syncthreads();
    // ---- LSTM cell on 4 threads (wave 0), publish h via sc1 stores ----
    if (tid < 4) {
      float gi = gsh[(tid << 2) + 0];
      float gf = gsh[(tid << 2) + 1];
      float gg = gsh[(tid << 2) + 2];
      float go = gsh[(tid << 2) + 3];
      float iv = sigmf(gi), fv = sigmf(gf), gv = tanhf(gg), ov = sigmf(go);
      ccell = fv * ccell + iv * gv;
      float hv = ov * tanhf(ccell);
      __hip_atomic_store(&hb[((t + 1) & 1) * HD + hu0 + tid], hv, RLX, AGT);
      if (dec) Adec[(size_t)(t - S) * HD + hu0 + tid] = f2bf(hv);
    }
    // arrival: drain wave 0's stores (covers lanes 0..3), then private flag
    if (tid == 0) {
      asm volatile("s_waitcnt vmcnt(0)" ::: "memory");
      __hip_atomic_store(&arrived[wg * FS], (unsigned)(t + 1), RLX, AGT);
    }
    // ---- waves 2-3: prefetch next token's embedding row during the wait ----
    if (!dec && (t + 1) < S && tid >= 128) {
      int tok = state[t + 1];
      int i = tid - 128;
      ((float4*)(vec + HD))[i] = ((const float4*)(emb + (size_t)tok * ED))[i];
    }
    // ---- root WG0: per-lane spin on private arrived lines, then release ----
    if (wg == 0) {
      const unsigned tgt = (unsigned)(t + 1);
      while (__hip_atomic_load(&arrived[tid * FS], RLX, AGT) < tgt) {}
      __syncthreads();   // ALL 256 arrivals seen before ANY release store
      __hip_atomic_store(&flag[tid * FS], tgt, RLX, AGT);
    }
  }
}

// ---- output head GEMM: out[t][v] = Adec[t] . Wout[v] + bout[v] ----
// WG tile: 512 t x 64 v. Wave w: t in [w*128, w*128+128), v in [v0, v0+64).
// Per k-step (K=32): stage A-slice (512x32 bf16, padded stride) in LDS,
// 8 a-frags + 4 b-frags -> 32 MFMA per wave. Wout (206 MB) read exactly once.
#define AST 56   // Alds row stride in ushorts

__global__ __launch_bounds__(TPB)
void out_gemm(const unsigned short* __restrict__ Adec,
              const float* __restrict__ Wout,
              const float* __restrict__ bout,
              float* __restrict__ out,
              int V) {
  __shared__ __align__(16) unsigned short Alds[512 * AST]; // 56 KB
  const int tid  = threadIdx.x;
  const int wv   = tid >> 6;
  const int lane = tid & 63;
  const int col  = lane & 15;
  const int quad = lane >> 4;
  const int v0   = blockIdx.x * 64;

  f32x4 acc[4][8];
#pragma unroll
  for (int bt = 0; bt < 4; ++bt)
#pragma unroll
    for (int tt = 0; tt < 8; ++tt)
      acc[bt][tt] = (f32x4){0.f, 0.f, 0.f, 0.f};

  for (int k0 = 0; k0 < HD; k0 += 32) {
    __syncthreads();
    // stage A k-slice: 512 rows x 32 bf16 (4 x uint4 chunks per row)
#pragma unroll
    for (int i = 0; i < 8; ++i) {
      int id = tid + (i << 8);             // 0..2047
      int rt = id >> 2, c4 = id & 3;
      uint4 d = *(const uint4*)(Adec + rt * HD + k0 + (c4 << 3));
      *(uint4*)&Alds[rt * AST + (c4 << 3)] = d;
    }
    __syncthreads();
    // B fragments from global (fp32 -> bf16): lane l covers Wout[v0+bt*16+col][k0+quad*8 ..+7]
    short8 bf[4];
#pragma unroll
    for (int bt = 0; bt < 4; ++bt) {
      int v = v0 + (bt << 4) + col;
      if (v >= V) v = V - 1;
      const float4* wp = (const float4*)(Wout + (size_t)v * HD + k0 + (quad << 3));
      float4 w0 = wp[0], w1 = wp[1];
      short8 b;
      b[0] = (short)f2bf(w0.x); b[1] = (short)f2bf(w0.y);
      b[2] = (short)f2bf(w0.z); b[3] = (short)f2bf(w0.w);
      b[4] = (short)f2bf(w1.x); b[5] = (short)f2bf(w1.y);
      b[6] = (short)f2bf(w1.z); b[7] = (short)f2bf(w1.w);
      bf[bt] = b;
    }
#pragma unroll
    for (int tt = 0; tt < 8; ++tt) {
      int trow = (wv << 7) + (tt << 4) + col;
      short8 af = *(const short8*)&Alds[trow * AST + (quad << 3)];
#pragma unroll
      for (int bt = 0; bt < 4; ++bt)
        acc[bt][tt] = __builtin_amdgcn_mfma_f32_16x16x32_bf16(af, bf[bt], acc[bt][tt], 0, 0, 0);
    }
  }
  // epilogue: C/D layout col = lane&15 (v), row = quad*4 + reg (t)
#pragma unroll
  for (int bt = 0; bt < 4; ++bt) {
    int v = v0 + (bt << 4) + col;
    if (v < V) {
      float bb = bout[v];
#pragma unroll
      for (int tt = 0; tt < 8; ++tt) {
        int tb = (wv << 7) + (tt << 4) + (quad << 2);
        f32x4 a = acc[bt][tt];
        out[(size_t)(tb + 0) * V + v] = a[0] + bb;
        out[(size_t)(tb + 1) * V + v] = a[1] + bb;
        out[(size_t)(tb + 2) * V + v] = a[2] + bb;
        out[(size_t)(tb + 3) * V + v] = a[3] + bb;
      }
    }
  }
}

// ---- row softmax in place over d_out: one WG per t ----
__global__ __launch_bounds__(TPB)
void softmax_rows(float* __restrict__ out, int V) {
  float* rowp = out + (size_t)blockIdx.x * V;
  __shared__ float red[8];
  const int tid = threadIdx.x;

  float m = -1e30f;
  for (int v = tid; v < V; v += TPB) m = fmaxf(m, rowp[v]);
#pragma unroll
  for (int off = 32; off >= 1; off >>= 1) m = fmaxf(m, __shfl_xor(m, off));
  if ((tid & 63) == 0) red[tid >> 6] = m;
  __syncthreads();
  if (tid == 0) red[4] = fmaxf(fmaxf(red[0], red[1]), fmaxf(red[2], red[3]));
  __syncthreads();
  m = red[4];

  float s = 0.0f;
  for (int v = tid; v < V; v += TPB) {
    float e = expf(rowp[v] - m);
    rowp[v] = e;
    s += e;
  }
#pragma unroll
  for (int off = 32; off >= 1; off >>= 1) s += __shfl_xor(s, off);
  if ((tid & 63) == 0) red[tid >> 6] = s;
  __syncthreads();
  if (tid == 0) red[5] = red[0] + red[1] + red[2] + red[3];
  __syncthreads();
  float inv = 1.0f / red[5];
  for (int v = tid; v < V; v += TPB) rowp[v] *= inv;
}

extern "C" void kernel_launch(void* const* d_in, const int* in_sizes, int n_in,
                              void* d_out, int out_size, void* d_ws, size_t ws_size,
                              hipStream_t stream) {
  const int*   state  = (const int*)d_in[0];
  // d_in[1] = max_len scalar (T derived from out_size instead)
  const float* emb    = (const float*)d_in[2];
  const float* encWih = (const float*)d_in[3];
  const float* encWhh = (const float*)d_in[4];
  const float* encbih = (const float*)d_in[5];
  const float* encbhh = (const float*)d_in[6];
  // d_in[7] = dec_Wih (multiplied by zero input in reference -> unused)
  const float* decWhh = (const float*)d_in[8];
  const float* decbih = (const float*)d_in[9];
  const float* decbhh = (const float*)d_in[10];
  const float* Wout   = (const float*)d_in[11];
  const float* bout   = (const float*)d_in[12];
  float*       out    = (float*)d_out;

  const int S = in_sizes[0];          // 2048
  const int V = in_sizes[12];         // 50257
  const int T = out_size / V;         // 512

  // zero flags + hb (ws is re-poisoned to 0xAA before every timed call)
  hipMemsetAsync(d_ws, 0, 49152, stream);
  unsigned*       arrived = (unsigned*)d_ws;
  unsigned*       flag    = (unsigned*)((char*)d_ws + 16384);
  float*          hb      = (float*)((char*)d_ws + 32768);
  unsigned short* Adec    = (unsigned short*)((char*)d_ws + 49152);

  rnn_kernel<<<NWG, TPB, 0, stream>>>(state, emb, encWih, encWhh, encbih, encbhh,
                                      decWhh, decbih, decbhh, arrived, flag, hb, Adec, S, T);
  int nvb = (V + 63) / 64;
  out_gemm<<<nvb, TPB, 0, stream>>>(Adec, Wout, bout, out, V);
  softmax_rows<<<T, TPB, 0, stream>>>(out, V);
}

// Round 3
// 8163.489 us; speedup vs baseline: 3.6582x; 1.1471x over previous
//
#include <hip/hip_runtime.h>
#include <stdint.h>
#include <math.h>

// Seq2seq LSTM: persistent-grid recurrence (enc 2048 + dec 512 steps).
// Round-3 design: NO barrier at all — dataflow sync. Each WG owns 4 hidden
// units and publishes them as 16B (2 x u64 relaxed agent-scope stores) to a
// private 64B line in a 4-slot rotating buffer pre-filled with the sentinel
// 0x7F7F7F7F (3.39e38 — impossible for |h|<1). Consumers poll lines directly:
// producer-store -> consumer-poll is ONE LLC hop each way. Slot reuse safety:
// a WG that has gathered h_t has transitive proof every WG finished reading
// slot (t+2)&3 (it held h_{t-2}); the WG re-sentinels its own line there,
// drained by vmcnt(0) before the next publish (hidden under the dot).
// Weights live in 96 fp32 VGPRs per thread (not LDS): kills the 4-way vec
// bank conflicts (now canonical 16B-stride b128 reads) and all bf16 unpack.
//
// ws: [0]      hlines: 4 slots x 256 WG x 64B = 64 KB (memset 0x7F)
//     [65536]  Adec: T x 1024 bf16 decoder hidden states (1 MB)

typedef __attribute__((ext_vector_type(8))) short short8;
typedef __attribute__((ext_vector_type(4))) float f32x4;
typedef unsigned long long u64;

#define HD 1024
#define ED 512
#define TPB 256
#define NWG 256
#define SENT64 0x7F7F7F7F7F7F7F7FULL

#define AGT __HIP_MEMORY_SCOPE_AGENT
#define RLX __ATOMIC_RELAXED

__device__ __forceinline__ unsigned short f2bf(float f) {
  union { float f; unsigned u; } x; x.f = f;
  unsigned u = x.u;
  u += 0x7fffu + ((u >> 16) & 1u);        // RNE
  return (unsigned short)(u >> 16);
}
__device__ __forceinline__ float sigmf(float x) { return 1.0f / (1.0f + expf(-x)); }

__global__ __launch_bounds__(TPB)
void rnn_kernel(const int* __restrict__ state,
                const float* __restrict__ emb,
                const float* __restrict__ encWih,
                const float* __restrict__ encWhh,
                const float* __restrict__ encbih,
                const float* __restrict__ encbhh,
                const float* __restrict__ decWhh,
                const float* __restrict__ decbih,
                const float* __restrict__ decbhh,
                u64* __restrict__ hlines,          // [4][256] 64B lines
                unsigned short* __restrict__ Adec, // [T][1024] bf16
                int S, int T) {
  __shared__ __align__(16) float vec[1536];   // [h(1024) | x(512)]
  __shared__ float gsh[16];

  const int tid = threadIdx.x;
  const int wg  = blockIdx.x;
  const int row = tid >> 4;            // gate row 0..15 of this WG
  const int c   = tid & 15;            // 16 lanes per row
  // LDS row r <-> global gate row: gt = r&3 (i,f,g,o), u = r>>2
  const int grow = (row & 3) * HD + (wg << 2) + (row >> 2);

  // ---- weights in registers: 24 x float4 = 96 fp32 VGPRs ----
  float4 w[24];
#pragma unroll
  for (int j = 0; j < 16; ++j)
    w[j] = *(const float4*)&encWhh[(size_t)grow * HD + 4 * (c + 16 * j)];
#pragma unroll
  for (int j = 16; j < 24; ++j)
    w[j] = *(const float4*)&encWih[(size_t)grow * ED + 4 * (c + 16 * j) - HD];
  float breg = encbih[grow] + encbhh[grow];

  float ccell = 0.0f;                  // cell state (threads 0..3 only)

  for (int t = 0; t < S + T; ++t) {
    const bool dec = (t >= S);
    if (t == S) {                      // decoder weight switch (one-time)
#pragma unroll
      for (int j = 0; j < 16; ++j)
        w[j] = *(const float4*)&decWhh[(size_t)grow * HD + 4 * (c + 16 * j)];
      breg = decbih[grow] + decbhh[grow];
    }

    // ---- gather h_t (and x_t for encoder) into vec ----
    if (t == 0) {
      *(float4*)&vec[4 * tid] = make_float4(0.f, 0.f, 0.f, 0.f);
      if (tid >= 128) {
        int tok = state[0];
        *(float4*)&vec[HD + 4 * (tid - 128)] =
            *(const float4*)&emb[(size_t)tok * ED + 4 * (tid - 128)];
      }
    } else {
      float4 xv;
      const bool havex = (!dec) && (tid >= 128);
      if (havex) {                     // issue emb load BEFORE the poll (overlaps)
        int tok = state[t];
        xv = *(const float4*)&emb[(size_t)tok * ED + 4 * (tid - 128)];
      }
      const u64* L = hlines + (((size_t)(t & 3) << 8) + tid) * 8;
      u64 d0, d1;
      do {
        d0 = __hip_atomic_load(&L[0], RLX, AGT);
        d1 = __hip_atomic_load(&L[1], RLX, AGT);
      } while (d0 == SENT64 || d1 == SENT64);
      union { u64 u; float2 f; } a, b;
      a.u = d0; b.u = d1;
      *(float2*)&vec[4 * tid + 0] = a.f;
      *(float2*)&vec[4 * tid + 2] = b.f;
      if (havex) *(float4*)&vec[HD + 4 * (tid - 128)] = xv;
    }
    // ---- re-sentinel own line in slot (t+2)&3 (off critical path) ----
    if (tid == 0) {
      u64* C = hlines + (((size_t)((t + 2) & 3) << 8) + wg) * 8;
      __hip_atomic_store(&C[0], SENT64, RLX, AGT);
      __hip_atomic_store(&C[1], SENT64, RLX, AGT);
    }
    __syncthreads();

    // ---- dot: row x vec, 4-float chunks at canonical 16B lane stride ----
    float a0 = (c == 0) ? breg : 0.0f, a1 = 0.f, a2 = 0.f, a3 = 0.f;
    if (!dec) {
#pragma unroll
      for (int j = 0; j < 24; j += 4) {
        float4 v0 = *(const float4*)&vec[4 * (c + 16 * (j + 0))];
        float4 v1 = *(const float4*)&vec[4 * (c + 16 * (j + 1))];
        float4 v2 = *(const float4*)&vec[4 * (c + 16 * (j + 2))];
        float4 v3 = *(const float4*)&vec[4 * (c + 16 * (j + 3))];
        float4 w0 = w[j + 0], w1 = w[j + 1], w2 = w[j + 2], w3 = w[j + 3];
        a0 = fmaf(w0.x, v0.x, fmaf(w0.y, v0.y, fmaf(w0.z, v0.z, fmaf(w0.w, v0.w, a0))));
        a1 = fmaf(w1.x, v1.x, fmaf(w1.y, v1.y, fmaf(w1.z, v1.z, fmaf(w1.w, v1.w, a1))));
        a2 = fmaf(w2.x, v2.x, fmaf(w2.y, v2.y, fmaf(w2.z, v2.z, fmaf(w2.w, v2.w, a2))));
        a3 = fmaf(w3.x, v3.x, fmaf(w3.y, v3.y, fmaf(w3.z, v3.z, fmaf(w3.w, v3.w, a3))));
      }
    } else {
#pragma unroll
      for (int j = 0; j < 16; j += 4) {
        float4 v0 = *(const float4*)&vec[4 * (c + 16 * (j + 0))];
        float4 v1 = *(const float4*)&vec[4 * (c + 16 * (j + 1))];
        float4 v2 = *(const float4*)&vec[4 * (c + 16 * (j + 2))];
        float4 v3 = *(const float4*)&vec[4 * (c + 16 * (j + 3))];
        float4 w0 = w[j + 0], w1 = w[j + 1], w2 = w[j + 2], w3 = w[j + 3];
        a0 = fmaf(w0.x, v0.x, fmaf(w0.y, v0.y, fmaf(w0.z, v0.z, fmaf(w0.w, v0.w, a0))));
        a1 = fmaf(w1.x, v1.x, fmaf(w1.y, v1.y, fmaf(w1.z, v1.z, fmaf(w1.w, v1.w, a1))));
        a2 = fmaf(w2.x, v2.x, fmaf(w2.y, v2.y, fmaf(w2.z, v2.z, fmaf(w2.w, v2.w, a2))));
        a3 = fmaf(w3.x, v3.x, fmaf(w3.y, v3.y, fmaf(w3.z, v3.z, fmaf(w3.w, v3.w, a3))));
      }
    }
    float acc = (a0 + a1) + (a2 + a3);
    acc += __shfl_xor(acc, 1);
    acc += __shfl_xor(acc, 2);
    acc += __shfl_xor(acc, 4);
    acc += __shfl_xor(acc, 8);
    if (c == 0) gsh[row] = acc;
    __syncthreads();

    // ---- LSTM cell on 4 threads; publish via wave-0 shuffle + tid0 store ----
    float hv = 0.0f;
    if (tid < 4) {
      float gi = gsh[(tid << 2) + 0];
      float gf = gsh[(tid << 2) + 1];
      float gg = gsh[(tid << 2) + 2];
      float go = gsh[(tid << 2) + 3];
      float iv = sigmf(gi), fv = sigmf(gf), gv = tanhf(gg), ov = sigmf(go);
      ccell = fv * ccell + iv * gv;
      hv = ov * tanhf(ccell);
      if (dec) Adec[(size_t)(t - S) * HD + (wg << 2) + tid] = f2bf(hv);
    }
    if (tid < 64) {
      float h0 = __shfl(hv, 0), h1 = __shfl(hv, 1);
      float h2 = __shfl(hv, 2), h3 = __shfl(hv, 3);
      if (tid == 0) {
        // drain the sentinel-clear (and everything else) before publishing
        asm volatile("s_waitcnt vmcnt(0)" ::: "memory");
        u64* P = hlines + (((size_t)((t + 1) & 3) << 8) + wg) * 8;
        union { float2 f; u64 u; } p0, p1;
        p0.f = make_float2(h0, h1); p1.f = make_float2(h2, h3);
        __hip_atomic_store(&P[0], p0.u, RLX, AGT);
        __hip_atomic_store(&P[1], p1.u, RLX, AGT);
      }
    }
  }
}

// ---- output head GEMM: out[t][v] = Adec[t] . Wout[v] + bout[v] ----
// WG tile: 512 t x 64 v. Wave w: t in [w*128, w*128+128), v in [v0, v0+64).
// Per k-step (K=32): stage A-slice (512x32 bf16, padded stride) in LDS,
// 8 a-frags + 4 b-frags -> 32 MFMA per wave. Wout (206 MB) read exactly once.
#define AST 56   // Alds row stride in ushorts

__global__ __launch_bounds__(TPB)
void out_gemm(const unsigned short* __restrict__ Adec,
              const float* __restrict__ Wout,
              const float* __restrict__ bout,
              float* __restrict__ out,
              int V) {
  __shared__ __align__(16) unsigned short Alds[512 * AST]; // 56 KB
  const int tid  = threadIdx.x;
  const int wv   = tid >> 6;
  const int lane = tid & 63;
  const int col  = lane & 15;
  const int quad = lane >> 4;
  const int v0   = blockIdx.x * 64;

  f32x4 acc[4][8];
#pragma unroll
  for (int bt = 0; bt < 4; ++bt)
#pragma unroll
    for (int tt = 0; tt < 8; ++tt)
      acc[bt][tt] = (f32x4){0.f, 0.f, 0.f, 0.f};

  for (int k0 = 0; k0 < HD; k0 += 32) {
    __syncthreads();
    // stage A k-slice: 512 rows x 32 bf16 (4 x uint4 chunks per row)
#pragma unroll
    for (int i = 0; i < 8; ++i) {
      int id = tid + (i << 8);             // 0..2047
      int rt = id >> 2, c4 = id & 3;
      uint4 d = *(const uint4*)(Adec + rt * HD + k0 + (c4 << 3));
      *(uint4*)&Alds[rt * AST + (c4 << 3)] = d;
    }
    __syncthreads();
    // B fragments from global (fp32 -> bf16): lane l covers Wout[v0+bt*16+col][k0+quad*8 ..+7]
    short8 bf[4];
#pragma unroll
    for (int bt = 0; bt < 4; ++bt) {
      int v = v0 + (bt << 4) + col;
      if (v >= V) v = V - 1;
      const float4* wp = (const float4*)(Wout + (size_t)v * HD + k0 + (quad << 3));
      float4 w0 = wp[0], w1 = wp[1];
      short8 b;
      b[0] = (short)f2bf(w0.x); b[1] = (short)f2bf(w0.y);
      b[2] = (short)f2bf(w0.z); b[3] = (short)f2bf(w0.w);
      b[4] = (short)f2bf(w1.x); b[5] = (short)f2bf(w1.y);
      b[6] = (short)f2bf(w1.z); b[7] = (short)f2bf(w1.w);
      bf[bt] = b;
    }
#pragma unroll
    for (int tt = 0; tt < 8; ++tt) {
      int trow = (wv << 7) + (tt << 4) + col;
      short8 af = *(const short8*)&Alds[trow * AST + (quad << 3)];
#pragma unroll
      for (int bt = 0; bt < 4; ++bt)
        acc[bt][tt] = __builtin_amdgcn_mfma_f32_16x16x32_bf16(af, bf[bt], acc[bt][tt], 0, 0, 0);
    }
  }
  // epilogue: C/D layout col = lane&15 (v), row = quad*4 + reg (t)
#pragma unroll
  for (int bt = 0; bt < 4; ++bt) {
    int v = v0 + (bt << 4) + col;
    if (v < V) {
      float bb = bout[v];
#pragma unroll
      for (int tt = 0; tt < 8; ++tt) {
        int tb = (wv << 7) + (tt << 4) + (quad << 2);
        f32x4 a = acc[bt][tt];
        out[(size_t)(tb + 0) * V + v] = a[0] + bb;
        out[(size_t)(tb + 1) * V + v] = a[1] + bb;
        out[(size_t)(tb + 2) * V + v] = a[2] + bb;
        out[(size_t)(tb + 3) * V + v] = a[3] + bb;
      }
    }
  }
}

// ---- row softmax in place over d_out: one WG per t ----
__global__ __launch_bounds__(TPB)
void softmax_rows(float* __restrict__ out, int V) {
  float* rowp = out + (size_t)blockIdx.x * V;
  __shared__ float red[8];
  const int tid = threadIdx.x;

  float m = -1e30f;
  for (int v = tid; v < V; v += TPB) m = fmaxf(m, rowp[v]);
#pragma unroll
  for (int off = 32; off >= 1; off >>= 1) m = fmaxf(m, __shfl_xor(m, off));
  if ((tid & 63) == 0) red[tid >> 6] = m;
  __syncthreads();
  if (tid == 0) red[4] = fmaxf(fmaxf(red[0], red[1]), fmaxf(red[2], red[3]));
  __syncthreads();
  m = red[4];

  float s = 0.0f;
  for (int v = tid; v < V; v += TPB) {
    float e = expf(rowp[v] - m);
    rowp[v] = e;
    s += e;
  }
#pragma unroll
  for (int off = 32; off >= 1; off >>= 1) s += __shfl_xor(s, off);
  if ((tid & 63) == 0) red[tid >> 6] = s;
  __syncthreads();
  if (tid == 0) red[5] = red[0] + red[1] + red[2] + red[3];
  __syncthreads();
  float inv = 1.0f / red[5];
  for (int v = tid; v < V; v += TPB) rowp[v] *= inv;
}

extern "C" void kernel_launch(void* const* d_in, const int* in_sizes, int n_in,
                              void* d_out, int out_size, void* d_ws, size_t ws_size,
                              hipStream_t stream) {
  const int*   state  = (const int*)d_in[0];
  // d_in[1] = max_len scalar (T derived from out_size instead)
  const float* emb    = (const float*)d_in[2];
  const float* encWih = (const float*)d_in[3];
  const float* encWhh = (const float*)d_in[4];
  const float* encbih = (const float*)d_in[5];
  const float* encbhh = (const float*)d_in[6];
  // d_in[7] = dec_Wih (multiplied by zero input in reference -> unused)
  const float* decWhh = (const float*)d_in[8];
  const float* decbih = (const float*)d_in[9];
  const float* decbhh = (const float*)d_in[10];
  const float* Wout   = (const float*)d_in[11];
  const float* bout   = (const float*)d_in[12];
  float*       out    = (float*)d_out;

  const int S = in_sizes[0];          // 2048
  const int V = in_sizes[12];         // 50257
  const int T = out_size / V;         // 512

  // sentinel-fill the h lines (0x7F byte pattern = 0x7F7F7F7F dwords)
  hipMemsetAsync(d_ws, 0x7F, 65536, stream);
  u64*            hlines = (u64*)d_ws;
  unsigned short* Adec   = (unsigned short*)((char*)d_ws + 65536);

  rnn_kernel<<<NWG, TPB, 0, stream>>>(state, emb, encWih, encWhh, encbih, encbhh,
                                      decWhh, decbih, decbhh, hlines, Adec, S, T);
  int nvb = (V + 63) / 64;
  out_gemm<<<nvb, TPB, 0, stream>>>(Adec, Wout, bout, out, V);
  softmax_rows<<<T, TPB, 0, stream>>>(out, V);
}